// Round 14
// baseline (11846.701 us; speedup 1.0000x reference)
//
#include <hip/hip_runtime.h>
#include <math.h>

#define B_   32
#define INS  1000
#define TS   999           // recurrent steps (t = 0..998)
#define D_   128
#define U_   512
#define G3   1536
#define OUTS 100
#define NB   208           // 16 LX + 64 L0 + 64 L1 + 64 L2
#define NTHR 512

// ws layout (floats)
#define HBUF_OFF 0                       // [4][3][512][32]  (step&3, layer, k, e)
#define HBUF_SZ  (4*3*512*32)
#define RING_OFF HBUF_SZ                 // [4][1536][32]    mx0 ring (step&3)
#define RING_SZ  (4*1536*32)
#define BAR_OFF  (RING_OFF + RING_SZ)    // 4096 u32 progress slots

// LDS layout (floats):
//  layer blocks: W [Ktot][24] @0 (j>=1: 24576; j=0: 12288)
//  part @24576: [sub8][g4][c8][e_pad36] = 9216
//  stage @33792: 3 x 2048 (8KB chunks = 64 rows x 32 e)     total 156 KiB
//  LX: W0 [128][96] @0; xbuf @12288 (2 x 4096)
#define PART_OFF  24576
#define STAGE_OFF 33792
#define SMEM_FLOATS 39936
#define PIDX4(s,g,c,e) ((((s)*4+(g))*8+(c))*36 + (e))
#define XBUF_OFF 12288

#define WT_STORE(p, v) __hip_atomic_store((p), (v), __ATOMIC_RELAXED, __HIP_MEMORY_SCOPE_AGENT)
#define CG_LOAD(p)     __hip_atomic_load((p), __ATOMIC_RELAXED, __HIP_MEMORY_SCOPE_AGENT)

// async global->LDS, 16B/lane: HW scatters lane i -> ldsbase + i*16 (m104)
#define GLOAD_LDS(G, L) __builtin_amdgcn_global_load_lds( \
  (const __attribute__((address_space(1))) void*)(G), \
  (__attribute__((address_space(3))) void*)(L), 16, 0, 0)

// counted waits (T4): never drain to 0 mid-pipeline; sched_barrier stops
// the compiler hoisting LDS reads above the wait (rule #18)
#define WAITV1 do { asm volatile("s_waitcnt vmcnt(1)" ::: "memory"); \
  __builtin_amdgcn_sched_barrier(0); } while (0)
#define WAITV0 do { asm volatile("s_waitcnt vmcnt(0)" ::: "memory"); \
  __builtin_amdgcn_sched_barrier(0); } while (0)

// one 64-row chunk of FMAs from staged LDS; gate-h goes into GH (xh or hh)
#define CHUNK_FMA(GH) { \
  const float* bp  = smem + STAGE_OFF + (c % 3) * 2048 + sub * 256 + eg * 4; \
  const float* wp2 = smem + (c * 64 + sub * 8) * 24 + c_l * 3; \
  _Pragma("unroll") \
  for (int rr = 0; rr < 8; ++rr) { \
    float4 av = *(const float4*)(bp + rr * 32); \
    float w0 = wp2[0], w1 = wp2[1], w2 = wp2[2]; \
    az[0]=fmaf(av.x,w0,az[0]); az[1]=fmaf(av.y,w0,az[1]); \
    az[2]=fmaf(av.z,w0,az[2]); az[3]=fmaf(av.w,w0,az[3]); \
    ar[0]=fmaf(av.x,w1,ar[0]); ar[1]=fmaf(av.y,w1,ar[1]); \
    ar[2]=fmaf(av.z,w1,ar[2]); ar[3]=fmaf(av.w,w1,ar[3]); \
    GH[0]=fmaf(av.x,w2,GH[0]); GH[1]=fmaf(av.y,w2,GH[1]); \
    GH[2]=fmaf(av.z,w2,GH[2]); GH[3]=fmaf(av.w,w2,GH[3]); \
    wp2 += 24; \
  } }

#define ISSUE_CHUNK(SRCBASE, CC) do { \
  const float* gsrc_ = (SRCBASE) + wv * 256 + lane * 4; \
  GLOAD_LDS(gsrc_, smem + STAGE_OFF + ((CC) % 3) * 2048 + wv * 256); \
} while (0)

__global__ void gru_init_kernel(const float* __restrict__ s0,
                                const float* __restrict__ s1,
                                const float* __restrict__ s2,
                                float* __restrict__ ws) {
  int g = blockIdx.x * 256 + threadIdx.x;
  if (g < 4096) { unsigned* bar = (unsigned*)(ws + BAR_OFF); bar[g] = 0u; }
  // h_j(-1) lives at ring parity (-1)&3 = 3, for all layers
  for (int i = g; i < 3 * 512 * 32; i += gridDim.x * 256) {
    int which = i / (512 * 32);
    int r = i - which * (512 * 32);
    int k = r >> 5, e = r & 31;
    const float* s = (which == 0) ? s0 : ((which == 1) ? s1 : s2);
    ws[HBUF_OFF + 3 * 49152 + which * 16384 + k * 32 + e] = s[k];
  }
}

// Self-timed dependency wait (r10). own >= t, up >= t+1, down >= t-3.
__device__ __forceinline__ void wait_deps(unsigned* slots, int role, int t) {
  const int tid = threadIdx.x;
  const unsigned* p = nullptr; int tgt = 0;
  if (role < 0) {
    if (tid < 64)       { p = &slots[(0   + tid)       * 16]; tgt = t - 3; }
  } else if (role == 0) {
    if (tid < 64)       { p = &slots[(0   + tid)       * 16]; tgt = t;     }
    else if (tid < 80)  { p = &slots[(192 + tid - 64)  * 16]; tgt = t + 1; }
    else if (tid < 144) { p = &slots[(64  + tid - 80)  * 16]; tgt = t - 3; }
  } else if (role == 1) {
    if (tid < 64)       { p = &slots[(64  + tid)       * 16]; tgt = t;     }
    else if (tid < 128) { p = &slots[(0   + tid - 64)  * 16]; tgt = t + 1; }
    else if (tid < 192) { p = &slots[(128 + tid - 128) * 16]; tgt = t - 3; }
  } else {
    if (tid < 64)       { p = &slots[(128 + tid)       * 16]; tgt = t;     }
    else if (tid < 128) { p = &slots[(64  + tid - 64)  * 16]; tgt = t + 1; }
  }
  if (p && tgt > 0) {
    while ((int)CG_LOAD(p) < tgt) __builtin_amdgcn_s_sleep(1);
  }
  __syncthreads();
  if (role >= 0) {
    if (threadIdx.x == 0) __builtin_amdgcn_fence(__ATOMIC_ACQUIRE, "agent");
    __syncthreads();
  }
}

__device__ __forceinline__ void publish(unsigned* slots, int sidx, int t) {
  __syncthreads();
  if (threadIdx.x == 0) WT_STORE(&slots[sidx * 16], (unsigned)(t + 1));
}

__global__ __launch_bounds__(NTHR, 1) void gru_persist(
    const float* __restrict__ x,
    const float* __restrict__ W0c, const float* __restrict__ U0c, const float* __restrict__ b0c,
    const float* __restrict__ W1c, const float* __restrict__ U1c, const float* __restrict__ b1c,
    const float* __restrict__ W2c, const float* __restrict__ U2c, const float* __restrict__ b2c,
    const float* __restrict__ Wd, const float* __restrict__ bd,
    float* __restrict__ out, float* __restrict__ ws)
{
  float* hbuf = ws + HBUF_OFF;
  float* ring = ws + RING_OFF;
  unsigned* slots = (unsigned*)(ws + BAR_OFF);
  float* pred_out = out;                       // [32][100][128]
  float* hid_out  = out + B_ * OUTS * D_;      // [32][100][3][512]

  const int bid = blockIdx.x;
  const int tid = threadIdx.x;

  int role, rb;
  if      (bid < 16)  { role = -1; rb = bid; }
  else if (bid < 80)  { role = 0;  rb = bid - 16; }
  else if (bid < 144) { role = 1;  rb = bid - 80; }
  else                { role = 2;  rb = bid - 144; }
  const int sidx = (role < 0) ? (192 + rb) : (role * 64 + rb);

  __shared__ float smem[SMEM_FLOATS];     // 156 KiB
  float* part = smem + PART_OFF;

  const int eg  = tid & 7;           // 4 batch elems (16B)
  const int c_l = (tid >> 3) & 7;    // output column
  const int sub = tid >> 6;          // 8-row sub-range within chunk (= wave)
  const int wv  = tid >> 6;          // wave id (staging)
  const int lane = tid & 63;
  const int cb  = (rb & 7) * 8 + (rb >> 3);
  const int c0  = cb * 8;
  const int rc = tid >> 5;
  const int re = tid & 31;
  const int xb0 = ((rb & 7) * 2 + (rb >> 3)) * 96;
  const int cg3 = (tid & 31) * 3;
  const int e0  = (tid >> 5) * 2;

  const float *Wj = nullptr, *Ujp = nullptr, *bj = nullptr;
  if      (role == 0) { Ujp = U0c; bj = b0c; }
  else if (role == 1) { Wj = W1c; Ujp = U1c; bj = b1c; }
  else if (role == 2) { Wj = W2c; Ujp = U2c; bj = b2c; }

  // ---- one-time staging ----
  if (role < 0) {
    for (int idx = tid; idx < 128 * 96; idx += NTHR)
      smem[idx] = W0c[(idx / 96) * G3 + xb0 + (idx % 96)];
    for (int f = tid; f < 1024; f += NTHR) {
      int e = f >> 5, d4 = (f & 31) * 4;
      *(float4*)(smem + XBUF_OFF + e * 128 + d4) =
          *(const float4*)(x + e * (INS * D_) + d4);
    }
  } else if (role == 0) {
    // rows 0..511 = U0, layout [row][c*3+g]
    for (int idx = tid; idx < 512 * 24; idx += NTHR) {
      int row = idx / 24, cg = idx - row * 24, cc = cg / 3, g = cg - cc * 3;
      smem[idx] = Ujp[row * G3 + g * 512 + c0 + cc];
    }
  } else {
    // rows 0..511 = Wj (x-side), 512..1023 = Ujp (h-side)
    for (int idx = tid; idx < 1024 * 24; idx += NTHR) {
      int row = idx / 24, cg = idx - row * 24, cc = cg / 3, g = cg - cc * 3;
      const float* mat = (row < 512) ? Wj : Ujp;
      int mr = (row < 512) ? row : row - 512;
      smem[idx] = mat[mr * G3 + g * 512 + c0 + cc];
    }
  }
  float bz = 0.f, br = 0.f, b0h = 0.f, b1h = 0.f;
  if (role >= 0 && tid < 256) {
    const int cg2 = c0 + rc;
    bz  = bj[cg2] + bj[G3 + cg2];
    br  = bj[512 + cg2] + bj[G3 + 512 + cg2];
    b0h = bj[1024 + cg2];
    b1h = bj[G3 + 1024 + cg2];
  }
  __syncthreads();

  // ---- self-timed step loop ----
  for (int t = 0; t < TS; ++t) {
    wait_deps(slots, role, t);

    if (role < 0) {
      float4 xp0, xp1;
      const bool pf = (t + 1) < TS;
      if (pf) {
        int f0 = tid, f1 = tid + 512;
        xp0 = *(const float4*)(x + (f0 >> 5) * (INS * D_) + (t + 1) * D_ + (f0 & 31) * 4);
        xp1 = *(const float4*)(x + (f1 >> 5) * (INS * D_) + (t + 1) * D_ + (f1 & 31) * 4);
      }
      const float* xb = smem + XBUF_OFF + (t & 1) * 4096;
      float acc[3][2];
      #pragma unroll
      for (int c = 0; c < 3; ++c) { acc[c][0] = 0.f; acc[c][1] = 0.f; }
      #pragma unroll 4
      for (int k4 = 0; k4 < D_; k4 += 4) {
        float4 v0 = *(const float4*)(xb + e0 * 128 + k4);
        float4 v1 = *(const float4*)(xb + (e0 + 1) * 128 + k4);
        float xs0[4] = {v0.x, v0.y, v0.z, v0.w};
        float xs1[4] = {v1.x, v1.y, v1.z, v1.w};
        #pragma unroll
        for (int kk = 0; kk < 4; ++kk) {
          const float* wpx = smem + (k4 + kk) * 96 + cg3;
          float w0 = wpx[0], w1 = wpx[1], w2 = wpx[2];
          acc[0][0] = fmaf(xs0[kk], w0, acc[0][0]);
          acc[0][1] = fmaf(xs1[kk], w0, acc[0][1]);
          acc[1][0] = fmaf(xs0[kk], w1, acc[1][0]);
          acc[1][1] = fmaf(xs1[kk], w1, acc[1][1]);
          acc[2][0] = fmaf(xs0[kk], w2, acc[2][0]);
          acc[2][1] = fmaf(xs1[kk], w2, acc[2][1]);
        }
      }
      float* dst = ring + (t & 3) * (G3 * 32);
      #pragma unroll
      for (int c = 0; c < 3; ++c) {
        WT_STORE(dst + (xb0 + cg3 + c) * 32 + e0,     acc[c][0]);
        WT_STORE(dst + (xb0 + cg3 + c) * 32 + e0 + 1, acc[c][1]);
      }
      if (pf) {
        float* xw = smem + XBUF_OFF + ((t + 1) & 1) * 4096;
        int f0 = tid, f1 = tid + 512;
        *(float4*)(xw + (f0 >> 5) * 128 + (f0 & 31) * 4) = xp0;
        *(float4*)(xw + (f1 >> 5) * 128 + (f1 & 31) * 4) = xp1;
      }
    } else {
      const int j = role;
      const float* hownb = hbuf + ((t + 3) & 3) * 49152 + j * 16384;       // h_j(t-1)
      const float* hupb  = (j > 0) ? (hbuf + (t & 3) * 49152 + (j - 1) * 16384)
                                   : nullptr;                              // h_{j-1}(t)

      float az[4] = {0,0,0,0}, ar[4] = {0,0,0,0};
      float axh[4] = {0,0,0,0}, ahh[4] = {0,0,0,0};

      if (j == 0) {
        // K=512 own-only: 8 chunks
        ISSUE_CHUNK(hownb + 0 * 2048, 0);
        ISSUE_CHUNK(hownb + 1 * 2048, 1);
        #pragma unroll
        for (int c = 0; c < 8; ++c) {
          if (c < 7) WAITV1; else WAITV0;
          __builtin_amdgcn_s_barrier();
          __builtin_amdgcn_sched_barrier(0);
          if (c + 2 < 8) ISSUE_CHUNK(hownb + (c + 2) * 2048, c + 2);
          CHUNK_FMA(ahh);
        }
      } else {
        // K=1024: chunks 0-7 = upstream (W rows), 8-15 = own (U rows)
        ISSUE_CHUNK(hupb + 0 * 2048, 0);
        ISSUE_CHUNK(hupb + 1 * 2048, 1);
        #pragma unroll
        for (int c = 0; c < 16; ++c) {
          if (c < 15) WAITV1; else WAITV0;
          __builtin_amdgcn_s_barrier();
          __builtin_amdgcn_sched_barrier(0);
          if (c + 2 < 16) {
            const float* nsrc = (c + 2 < 8) ? (hupb + (c + 2) * 2048)
                                            : (hownb + (c - 6) * 2048);
            ISSUE_CHUNK(nsrc, c + 2);
          }
          if (c < 8) { CHUNK_FMA(axh); } else { CHUNK_FMA(ahh); }
        }
      }

      // fresh-data scalar loads (plain, post-fence cached; after GEMM so the
      // counted vmcnt waits above saw only load_lds ops)
      float xz = 0.f, xr2 = 0.f, xhv0 = 0.f, hp = 0.f;
      if (tid < 256) {
        const int cg2 = c0 + rc;
        hp = hownb[cg2 * 32 + re];
        if (j == 0) {
          const float* r3 = ring + (t & 3) * (G3 * 32);
          xz   = r3[cg2 * 32 + re];
          xr2  = r3[(512 + cg2) * 32 + re];
          xhv0 = r3[(1024 + cg2) * 32 + re];
        }
      }

      *(float4*)&part[PIDX4(sub, 0, c_l, eg * 4)] = make_float4(az[0], az[1], az[2], az[3]);
      *(float4*)&part[PIDX4(sub, 1, c_l, eg * 4)] = make_float4(ar[0], ar[1], ar[2], ar[3]);
      if (j == 0) {
        *(float4*)&part[PIDX4(sub, 2, c_l, eg * 4)] = make_float4(ahh[0], ahh[1], ahh[2], ahh[3]);
      } else {
        *(float4*)&part[PIDX4(sub, 2, c_l, eg * 4)] = make_float4(axh[0], axh[1], axh[2], axh[3]);
        *(float4*)&part[PIDX4(sub, 3, c_l, eg * 4)] = make_float4(ahh[0], ahh[1], ahh[2], ahh[3]);
      }
      __syncthreads();

      if (tid < 256) {
        float gz = 0.f, gr = 0.f, xh = 0.f, hh = 0.f;
        #pragma unroll
        for (int s2 = 0; s2 < 8; ++s2) {
          gz += part[PIDX4(s2, 0, rc, re)];
          gr += part[PIDX4(s2, 1, rc, re)];
          if (j == 0) {
            hh += part[PIDX4(s2, 2, rc, re)];
          } else {
            xh += part[PIDX4(s2, 2, rc, re)];
            hh += part[PIDX4(s2, 3, rc, re)];
          }
        }
        const int cg2 = c0 + rc;
        const float xhv = (j == 0) ? xhv0 : xh;
        const float zi = gz + xz + bz;
        const float ri = gr + xr2 + br;
        const float z = 1.f / (1.f + expf(-zi));
        const float r = 1.f / (1.f + expf(-ri));
        const float cand = tanhf((xhv + b0h) + r * (hh + b1h));
        const float hn = z * hp + (1.f - z) * cand;
        WT_STORE(&hbuf[(t & 3) * 49152 + j * 16384 + cg2 * 32 + re], hn);
        if (t >= TS - OUTS) {
          WT_STORE(&hid_out[((re * OUTS + (t - (TS - OUTS))) * 3 + j) * U_ + cg2], hn);
        }
      }
    }
    publish(slots, sidx, t);
  }

  // ---- readout ----
  if (tid < 64) {
    while ((int)CG_LOAD(&slots[(128 + tid) * 16]) < TS) __builtin_amdgcn_s_sleep(1);
  }
  __syncthreads();
  if (tid == 0) __builtin_amdgcn_fence(__ATOMIC_ACQUIRE, "agent");
  __syncthreads();

  const int gt = bid * NTHR + tid;
  for (int o = gt; o < B_ * OUTS * D_; o += NB * NTHR) {
    int b  = o / (OUTS * D_);
    int r2 = o - b * (OUTS * D_);
    int s  = r2 >> 7;
    int dd = r2 & 127;
    const float* ys = hid_out + ((b * OUTS + s) * 3 + 2) * U_;
    float acc = bd[dd];
    #pragma unroll 4
    for (int k = 0; k < U_; k += 4) {
      float4 yv = *(const float4*)(ys + k);
      acc = fmaf(yv.x, Wd[(k    ) * D_ + dd], acc);
      acc = fmaf(yv.y, Wd[(k + 1) * D_ + dd], acc);
      acc = fmaf(yv.z, Wd[(k + 2) * D_ + dd], acc);
      acc = fmaf(yv.w, Wd[(k + 3) * D_ + dd], acc);
    }
    pred_out[o] = acc;
  }
}

extern "C" void kernel_launch(void* const* d_in, const int* in_sizes, int n_in,
                              void* d_out, int out_size, void* d_ws, size_t ws_size,
                              hipStream_t stream) {
  const float* x  = (const float*)d_in[0];
  const float* W0 = (const float*)d_in[1];
  const float* U0 = (const float*)d_in[2];
  const float* b0 = (const float*)d_in[3];
  const float* s0 = (const float*)d_in[4];
  const float* W1 = (const float*)d_in[5];
  const float* U1 = (const float*)d_in[6];
  const float* b1 = (const float*)d_in[7];
  const float* s1 = (const float*)d_in[8];
  const float* W2 = (const float*)d_in[9];
  const float* U2 = (const float*)d_in[10];
  const float* b2 = (const float*)d_in[11];
  const float* s2 = (const float*)d_in[12];
  const float* Wd = (const float*)d_in[13];
  const float* bd = (const float*)d_in[14];
  float* ws = (float*)d_ws;

  gru_init_kernel<<<192, 256, 0, stream>>>(s0, s1, s2, ws);
  gru_persist<<<NB, NTHR, 0, stream>>>(x, W0, U0, b0, W1, U1, b1,
                                       W2, U2, b2, Wd, bd, (float*)d_out, ws);
}

// Round 15
// 9714.030 us; speedup vs baseline: 1.2195x; 1.2195x over previous
//
#include <hip/hip_runtime.h>
#include <math.h>

#define B_   32
#define INS  1000
#define TS   999           // recurrent steps (t = 0..998)
#define D_   128
#define U_   512
#define G3   1536
#define OUTS 100
#define NB   208           // 16 LX + 64 L0 + 64 L1 + 64 L2
#define NTHR 512

// ws layout (floats)
#define HBUF_OFF 0                       // [4][3][512][32]  (step&3, layer, k, e)
#define HBUF_SZ  (4*3*512*32)
#define RING_OFF HBUF_SZ                 // [4][1536][32]    mx0 ring (step&3)
#define RING_SZ  (4*1536*32)
#define BAR_OFF  (RING_OFF + RING_SZ)    // 4096 u32 progress slots

// LDS layout (floats):
//  j>=1: W [1024][24] @0 = 24576; stage @24576: 6 x 2048 = 12288 (48KB)
//  j==0: W [512][24]  @0 = 12288; stage @12288: 6 x 2048
//  part ALIASED into stage region (stage dead when part is live; barrier between)
//  LX: W0 [128][96] @0 = 12288; xbuf @12288: 2 x 4096
#define SMEM_FLOATS 36864
#define PIDX4(s,g,c,e) ((((s)*4+(g))*8+(c))*36 + (e))
#define XBUF_OFF 12288

#define WT_STORE(p, v) __hip_atomic_store((p), (v), __ATOMIC_RELAXED, __HIP_MEMORY_SCOPE_AGENT)
#define CG_LOAD(p)     __hip_atomic_load((p), __ATOMIC_RELAXED, __HIP_MEMORY_SCOPE_AGENT)

// async global->LDS, 16B/lane: lane i -> ldsbase + i*16 (m104); per-wave vmcnt
#define GLOAD_LDS(G, L) __builtin_amdgcn_global_load_lds( \
  (const __attribute__((address_space(1))) void*)(G), \
  (__attribute__((address_space(3))) void*)(L), 16, 0, 0)

// counted wait (T4) + sched fence (rule #18)
#define WAITVN(N) do { asm volatile("s_waitcnt vmcnt(" #N ")" ::: "memory"); \
  __builtin_amdgcn_sched_barrier(0); } while (0)
// N = min(5, NCH-1-c), compile-time under full unroll
#define WAIT_FOR(C, NCH) do { \
  if ((NCH) - 1 - (C) >= 5)      { WAITVN(5); } \
  else if ((NCH) - 1 - (C) == 4) { WAITVN(4); } \
  else if ((NCH) - 1 - (C) == 3) { WAITVN(3); } \
  else if ((NCH) - 1 - (C) == 2) { WAITVN(2); } \
  else if ((NCH) - 1 - (C) == 1) { WAITVN(1); } \
  else                           { WAITVN(0); } } while (0)

// one 64-row chunk: this wave consumes exactly the 8 rows it staged
#define CHUNK_FMA8(C, GH) { \
  const float* bp  = stg + ((C) % 6) * 2048 + sub * 256 + eg * 4; \
  const float* wp2 = smem + ((C) * 64 + sub * 8) * 24 + c_l * 3; \
  _Pragma("unroll") \
  for (int rr = 0; rr < 8; ++rr) { \
    float4 av = *(const float4*)(bp + rr * 32); \
    float w0 = wp2[0], w1 = wp2[1], w2 = wp2[2]; \
    az[0]=fmaf(av.x,w0,az[0]); az[1]=fmaf(av.y,w0,az[1]); \
    az[2]=fmaf(av.z,w0,az[2]); az[3]=fmaf(av.w,w0,az[3]); \
    ar[0]=fmaf(av.x,w1,ar[0]); ar[1]=fmaf(av.y,w1,ar[1]); \
    ar[2]=fmaf(av.z,w1,ar[2]); ar[3]=fmaf(av.w,w1,ar[3]); \
    GH[0]=fmaf(av.x,w2,GH[0]); GH[1]=fmaf(av.y,w2,GH[1]); \
    GH[2]=fmaf(av.z,w2,GH[2]); GH[3]=fmaf(av.w,w2,GH[3]); \
    wp2 += 24; \
  } }

#define ISSUE_CHUNK(SRCBASE, CC) do { \
  const float* gsrc_ = (SRCBASE) + wv * 256 + lane * 4; \
  GLOAD_LDS(gsrc_, stg + ((CC) % 6) * 2048 + wv * 256); \
} while (0)

__global__ void gru_init_kernel(const float* __restrict__ s0,
                                const float* __restrict__ s1,
                                const float* __restrict__ s2,
                                float* __restrict__ ws) {
  int g = blockIdx.x * 256 + threadIdx.x;
  if (g < 4096) { unsigned* bar = (unsigned*)(ws + BAR_OFF); bar[g] = 0u; }
  // h_j(-1) lives at ring parity (-1)&3 = 3, for all layers
  for (int i = g; i < 3 * 512 * 32; i += gridDim.x * 256) {
    int which = i / (512 * 32);
    int r = i - which * (512 * 32);
    int k = r >> 5, e = r & 31;
    const float* s = (which == 0) ? s0 : ((which == 1) ? s1 : s2);
    ws[HBUF_OFF + 3 * 49152 + which * 16384 + k * 32 + e] = s[k];
  }
}

// Self-timed dependency wait (r10). own >= t, up >= t+1, down >= t-3.
__device__ __forceinline__ void wait_deps(unsigned* slots, int role, int t) {
  const int tid = threadIdx.x;
  const unsigned* p = nullptr; int tgt = 0;
  if (role < 0) {
    if (tid < 64)       { p = &slots[(0   + tid)       * 16]; tgt = t - 3; }
  } else if (role == 0) {
    if (tid < 64)       { p = &slots[(0   + tid)       * 16]; tgt = t;     }
    else if (tid < 80)  { p = &slots[(192 + tid - 64)  * 16]; tgt = t + 1; }
    else if (tid < 144) { p = &slots[(64  + tid - 80)  * 16]; tgt = t - 3; }
  } else if (role == 1) {
    if (tid < 64)       { p = &slots[(64  + tid)       * 16]; tgt = t;     }
    else if (tid < 128) { p = &slots[(0   + tid - 64)  * 16]; tgt = t + 1; }
    else if (tid < 192) { p = &slots[(128 + tid - 128) * 16]; tgt = t - 3; }
  } else {
    if (tid < 64)       { p = &slots[(128 + tid)       * 16]; tgt = t;     }
    else if (tid < 128) { p = &slots[(64  + tid - 64)  * 16]; tgt = t + 1; }
  }
  if (p && tgt > 0) {
    while ((int)CG_LOAD(p) < tgt) __builtin_amdgcn_s_sleep(1);
  }
  __syncthreads();
  if (role >= 0) {
    if (threadIdx.x == 0) __builtin_amdgcn_fence(__ATOMIC_ACQUIRE, "agent");
    __syncthreads();
  }
}

__device__ __forceinline__ void publish(unsigned* slots, int sidx, int t) {
  __syncthreads();
  if (threadIdx.x == 0) WT_STORE(&slots[sidx * 16], (unsigned)(t + 1));
}

__global__ __launch_bounds__(NTHR, 1) void gru_persist(
    const float* __restrict__ x,
    const float* __restrict__ W0c, const float* __restrict__ U0c, const float* __restrict__ b0c,
    const float* __restrict__ W1c, const float* __restrict__ U1c, const float* __restrict__ b1c,
    const float* __restrict__ W2c, const float* __restrict__ U2c, const float* __restrict__ b2c,
    const float* __restrict__ Wd, const float* __restrict__ bd,
    float* __restrict__ out, float* __restrict__ ws)
{
  float* hbuf = ws + HBUF_OFF;
  float* ring = ws + RING_OFF;
  unsigned* slots = (unsigned*)(ws + BAR_OFF);
  float* pred_out = out;                       // [32][100][128]
  float* hid_out  = out + B_ * OUTS * D_;      // [32][100][3][512]

  const int bid = blockIdx.x;
  const int tid = threadIdx.x;

  int role, rb;
  if      (bid < 16)  { role = -1; rb = bid; }
  else if (bid < 80)  { role = 0;  rb = bid - 16; }
  else if (bid < 144) { role = 1;  rb = bid - 80; }
  else                { role = 2;  rb = bid - 144; }
  const int sidx = (role < 0) ? (192 + rb) : (role * 64 + rb);

  __shared__ float smem[SMEM_FLOATS];     // 144 KiB
  float* stg  = smem + ((role == 0) ? 12288 : 24576);   // stage region (layer blocks)
  float* part = stg;                                    // ALIASED (barrier-separated)

  const int eg  = tid & 7;           // 4 batch elems (16B)
  const int c_l = (tid >> 3) & 7;    // output column
  const int sub = tid >> 6;          // 8-row sub-range within chunk (= wave)
  const int wv  = tid >> 6;          // wave id (staging)
  const int lane = tid & 63;
  const int cb  = (rb & 7) * 8 + (rb >> 3);
  const int c0  = cb * 8;
  const int rc = tid >> 5;
  const int re = tid & 31;
  const int xb0 = ((rb & 7) * 2 + (rb >> 3)) * 96;
  const int cg3 = (tid & 31) * 3;
  const int e0  = (tid >> 5) * 2;

  const float *Wj = nullptr, *Ujp = nullptr, *bj = nullptr;
  if      (role == 0) { Ujp = U0c; bj = b0c; }
  else if (role == 1) { Wj = W1c; Ujp = U1c; bj = b1c; }
  else if (role == 2) { Wj = W2c; Ujp = U2c; bj = b2c; }

  // ---- one-time staging ----
  if (role < 0) {
    for (int idx = tid; idx < 128 * 96; idx += NTHR)
      smem[idx] = W0c[(idx / 96) * G3 + xb0 + (idx % 96)];
    for (int f = tid; f < 1024; f += NTHR) {
      int e = f >> 5, d4 = (f & 31) * 4;
      *(float4*)(smem + XBUF_OFF + e * 128 + d4) =
          *(const float4*)(x + e * (INS * D_) + d4);
    }
  } else if (role == 0) {
    // rows 0..511 = U0, layout [row][c*3+g]
    for (int idx = tid; idx < 512 * 24; idx += NTHR) {
      int row = idx / 24, cg = idx - row * 24, cc = cg / 3, g = cg - cc * 3;
      smem[idx] = Ujp[row * G3 + g * 512 + c0 + cc];
    }
  } else {
    // rows 0..511 = Wj (x-side), 512..1023 = Ujp (h-side)
    for (int idx = tid; idx < 1024 * 24; idx += NTHR) {
      int row = idx / 24, cg = idx - row * 24, cc = cg / 3, g = cg - cc * 3;
      const float* mat = (row < 512) ? Wj : Ujp;
      int mr = (row < 512) ? row : row - 512;
      smem[idx] = mat[mr * G3 + g * 512 + c0 + cc];
    }
  }
  float bz = 0.f, br = 0.f, b0h = 0.f, b1h = 0.f;
  if (role >= 0 && tid < 256) {
    const int cg2 = c0 + rc;
    bz  = bj[cg2] + bj[G3 + cg2];
    br  = bj[512 + cg2] + bj[G3 + 512 + cg2];
    b0h = bj[1024 + cg2];
    b1h = bj[G3 + 1024 + cg2];
  }
  __syncthreads();

  // ---- self-timed step loop ----
  for (int t = 0; t < TS; ++t) {
    wait_deps(slots, role, t);

    if (role < 0) {
      float4 xp0, xp1;
      const bool pf = (t + 1) < TS;
      if (pf) {
        int f0 = tid, f1 = tid + 512;
        xp0 = *(const float4*)(x + (f0 >> 5) * (INS * D_) + (t + 1) * D_ + (f0 & 31) * 4);
        xp1 = *(const float4*)(x + (f1 >> 5) * (INS * D_) + (t + 1) * D_ + (f1 & 31) * 4);
      }
      const float* xb = smem + XBUF_OFF + (t & 1) * 4096;
      float acc[3][2];
      #pragma unroll
      for (int c = 0; c < 3; ++c) { acc[c][0] = 0.f; acc[c][1] = 0.f; }
      #pragma unroll 4
      for (int k4 = 0; k4 < D_; k4 += 4) {
        float4 v0 = *(const float4*)(xb + e0 * 128 + k4);
        float4 v1 = *(const float4*)(xb + (e0 + 1) * 128 + k4);
        float xs0[4] = {v0.x, v0.y, v0.z, v0.w};
        float xs1[4] = {v1.x, v1.y, v1.z, v1.w};
        #pragma unroll
        for (int kk = 0; kk < 4; ++kk) {
          const float* wpx = smem + (k4 + kk) * 96 + cg3;
          float w0 = wpx[0], w1 = wpx[1], w2 = wpx[2];
          acc[0][0] = fmaf(xs0[kk], w0, acc[0][0]);
          acc[0][1] = fmaf(xs1[kk], w0, acc[0][1]);
          acc[1][0] = fmaf(xs0[kk], w1, acc[1][0]);
          acc[1][1] = fmaf(xs1[kk], w1, acc[1][1]);
          acc[2][0] = fmaf(xs0[kk], w2, acc[2][0]);
          acc[2][1] = fmaf(xs1[kk], w2, acc[2][1]);
        }
      }
      float* dst = ring + (t & 3) * (G3 * 32);
      #pragma unroll
      for (int c = 0; c < 3; ++c) {
        WT_STORE(dst + (xb0 + cg3 + c) * 32 + e0,     acc[c][0]);
        WT_STORE(dst + (xb0 + cg3 + c) * 32 + e0 + 1, acc[c][1]);
      }
      if (pf) {
        float* xw = smem + XBUF_OFF + ((t + 1) & 1) * 4096;
        int f0 = tid, f1 = tid + 512;
        *(float4*)(xw + (f0 >> 5) * 128 + (f0 & 31) * 4) = xp0;
        *(float4*)(xw + (f1 >> 5) * 128 + (f1 & 31) * 4) = xp1;
      }
    } else {
      const int j = role;
      const float* hownb = hbuf + ((t + 3) & 3) * 49152 + j * 16384;       // h_j(t-1)
      const float* hupb  = (j > 0) ? (hbuf + (t & 3) * 49152 + (j - 1) * 16384)
                                   : nullptr;                              // h_{j-1}(t)

      float az[4] = {0,0,0,0}, ar[4] = {0,0,0,0};
      float axh[4] = {0,0,0,0}, ahh[4] = {0,0,0,0};

      if (j == 0) {
        // K=512 own-only: 8 chunks, depth 6, NO barriers (per-wave pipeline)
        ISSUE_CHUNK(hownb + 0 * 2048, 0); ISSUE_CHUNK(hownb + 1 * 2048, 1);
        ISSUE_CHUNK(hownb + 2 * 2048, 2); ISSUE_CHUNK(hownb + 3 * 2048, 3);
        ISSUE_CHUNK(hownb + 4 * 2048, 4); ISSUE_CHUNK(hownb + 5 * 2048, 5);
        #pragma unroll
        for (int c = 0; c < 8; ++c) {
          WAIT_FOR(c, 8);
          CHUNK_FMA8(c, ahh);
          __builtin_amdgcn_sched_barrier(0);
          if (c + 6 < 8) ISSUE_CHUNK(hownb + (c + 6) * 2048, c + 6);
        }
      } else {
        // K=1024: chunks 0-7 upstream (W rows), 8-15 own (U rows); depth 6
        ISSUE_CHUNK(hupb + 0 * 2048, 0); ISSUE_CHUNK(hupb + 1 * 2048, 1);
        ISSUE_CHUNK(hupb + 2 * 2048, 2); ISSUE_CHUNK(hupb + 3 * 2048, 3);
        ISSUE_CHUNK(hupb + 4 * 2048, 4); ISSUE_CHUNK(hupb + 5 * 2048, 5);
        #pragma unroll
        for (int c = 0; c < 16; ++c) {
          WAIT_FOR(c, 16);
          if (c < 8) { CHUNK_FMA8(c, axh); } else { CHUNK_FMA8(c, ahh); }
          __builtin_amdgcn_sched_barrier(0);
          if (c + 6 < 16) {
            const int cc = c + 6;
            const float* nsrc = (cc < 8) ? (hupb + cc * 2048)
                                         : (hownb + (cc - 8) * 2048);
            ISSUE_CHUNK(nsrc, cc);
          }
        }
      }

      // fresh-data scalar loads (after GEMM: counted vmcnt saw only load_lds)
      float xz = 0.f, xr2 = 0.f, xhv0 = 0.f, hp = 0.f;
      if (tid < 256) {
        const int cg2 = c0 + rc;
        hp = hownb[cg2 * 32 + re];
        if (j == 0) {
          const float* r3 = ring + (t & 3) * (G3 * 32);
          xz   = r3[cg2 * 32 + re];
          xr2  = r3[(512 + cg2) * 32 + re];
          xhv0 = r3[(1024 + cg2) * 32 + re];
        }
      }

      // stage region is dead now; barrier before aliased part writes
      __syncthreads();

      *(float4*)&part[PIDX4(sub, 0, c_l, eg * 4)] = make_float4(az[0], az[1], az[2], az[3]);
      *(float4*)&part[PIDX4(sub, 1, c_l, eg * 4)] = make_float4(ar[0], ar[1], ar[2], ar[3]);
      if (j == 0) {
        *(float4*)&part[PIDX4(sub, 2, c_l, eg * 4)] = make_float4(ahh[0], ahh[1], ahh[2], ahh[3]);
      } else {
        *(float4*)&part[PIDX4(sub, 2, c_l, eg * 4)] = make_float4(axh[0], axh[1], axh[2], axh[3]);
        *(float4*)&part[PIDX4(sub, 3, c_l, eg * 4)] = make_float4(ahh[0], ahh[1], ahh[2], ahh[3]);
      }
      __syncthreads();

      if (tid < 256) {
        float gz = 0.f, gr = 0.f, xh = 0.f, hh = 0.f;
        #pragma unroll
        for (int s2 = 0; s2 < 8; ++s2) {
          gz += part[PIDX4(s2, 0, rc, re)];
          gr += part[PIDX4(s2, 1, rc, re)];
          if (j == 0) {
            hh += part[PIDX4(s2, 2, rc, re)];
          } else {
            xh += part[PIDX4(s2, 2, rc, re)];
            hh += part[PIDX4(s2, 3, rc, re)];
          }
        }
        const int cg2 = c0 + rc;
        const float xhv = (j == 0) ? xhv0 : xh;
        const float zi = gz + xz + bz;
        const float ri = gr + xr2 + br;
        const float z = 1.f / (1.f + expf(-zi));
        const float r = 1.f / (1.f + expf(-ri));
        const float cand = tanhf((xhv + b0h) + r * (hh + b1h));
        const float hn = z * hp + (1.f - z) * cand;
        WT_STORE(&hbuf[(t & 3) * 49152 + j * 16384 + cg2 * 32 + re], hn);
        if (t >= TS - OUTS) {
          WT_STORE(&hid_out[((re * OUTS + (t - (TS - OUTS))) * 3 + j) * U_ + cg2], hn);
        }
      }
    }
    publish(slots, sidx, t);
  }

  // ---- readout ----
  if (tid < 64) {
    while ((int)CG_LOAD(&slots[(128 + tid) * 16]) < TS) __builtin_amdgcn_s_sleep(1);
  }
  __syncthreads();
  if (tid == 0) __builtin_amdgcn_fence(__ATOMIC_ACQUIRE, "agent");
  __syncthreads();

  const int gt = bid * NTHR + tid;
  for (int o = gt; o < B_ * OUTS * D_; o += NB * NTHR) {
    int b  = o / (OUTS * D_);
    int r2 = o - b * (OUTS * D_);
    int s  = r2 >> 7;
    int dd = r2 & 127;
    const float* ys = hid_out + ((b * OUTS + s) * 3 + 2) * U_;
    float acc = bd[dd];
    #pragma unroll 4
    for (int k = 0; k < U_; k += 4) {
      float4 yv = *(const float4*)(ys + k);
      acc = fmaf(yv.x, Wd[(k    ) * D_ + dd], acc);
      acc = fmaf(yv.y, Wd[(k + 1) * D_ + dd], acc);
      acc = fmaf(yv.z, Wd[(k + 2) * D_ + dd], acc);
      acc = fmaf(yv.w, Wd[(k + 3) * D_ + dd], acc);
    }
    pred_out[o] = acc;
  }
}

extern "C" void kernel_launch(void* const* d_in, const int* in_sizes, int n_in,
                              void* d_out, int out_size, void* d_ws, size_t ws_size,
                              hipStream_t stream) {
  const float* x  = (const float*)d_in[0];
  const float* W0 = (const float*)d_in[1];
  const float* U0 = (const float*)d_in[2];
  const float* b0 = (const float*)d_in[3];
  const float* s0 = (const float*)d_in[4];
  const float* W1 = (const float*)d_in[5];
  const float* U1 = (const float*)d_in[6];
  const float* b1 = (const float*)d_in[7];
  const float* s1 = (const float*)d_in[8];
  const float* W2 = (const float*)d_in[9];
  const float* U2 = (const float*)d_in[10];
  const float* b2 = (const float*)d_in[11];
  const float* s2 = (const float*)d_in[12];
  const float* Wd = (const float*)d_in[13];
  const float* bd = (const float*)d_in[14];
  float* ws = (float*)d_ws;

  gru_init_kernel<<<192, 256, 0, stream>>>(s0, s1, s2, ws);
  gru_persist<<<NB, NTHR, 0, stream>>>(x, W0, U0, b0, W1, U1, b1,
                                       W2, U2, b2, Wd, bd, (float*)d_out, ws);
}